// Round 19
// baseline (1257.639 us; speedup 1.0000x reference)
//
#include <hip/hip_runtime.h>
#include <hip/hip_bf16.h>
#include <math.h>

typedef __attribute__((ext_vector_type(8))) short short8v;
typedef __attribute__((ext_vector_type(4))) float f32x4;
typedef unsigned short u16;

__device__ __forceinline__ float gelu_f(float x) {
    return 0.5f * x * (1.0f + erff(x * 0.70710678118654752f));
}
__device__ __forceinline__ float bf2f(u16 u) {
    union { unsigned int i; float f; } v; v.i = ((unsigned int)u) << 16; return v.f;
}
__device__ __forceinline__ u16 f2bf(float f) {
    union { float f; unsigned int i; } v; v.f = f;
    unsigned int r = v.i + 0x7FFFu + ((v.i >> 16) & 1u);
    return (u16)(r >> 16);
}
__device__ __forceinline__ short8v negbf(short8v a) {
    uint4 u = *(uint4*)&a;
    u.x ^= 0x80008000u; u.y ^= 0x80008000u; u.z ^= 0x80008000u; u.w ^= 0x80008000u;
    return *(short8v*)&u;
}

// ---- typed 8-element (as packed bf16) loads, D reads, O stores ----
__device__ __forceinline__ uint4 load8(const u16* p) { return *(const uint4*)p; }
__device__ __forceinline__ uint4 load8(const float* p) {
    float4 a = *(const float4*)p;
    float4 b = *(const float4*)(p + 4);
    union { uint4 u; u16 e[8]; } r;
    r.e[0] = f2bf(a.x); r.e[1] = f2bf(a.y); r.e[2] = f2bf(a.z); r.e[3] = f2bf(a.w);
    r.e[4] = f2bf(b.x); r.e[5] = f2bf(b.y); r.e[6] = f2bf(b.z); r.e[7] = f2bf(b.w);
    return r.u;
}
__device__ __forceinline__ float rdD(const u16* p) { return bf2f(*p); }
__device__ __forceinline__ float rdD(const float* p) { return *p; }
__device__ __forceinline__ void stO(u16* p, float v) { *p = f2bf(v); }
__device__ __forceinline__ void stO(float* p, float v) { *p = v; }

// ============ typed MFMA GEMM (R5-proven structure, 64x64 tile) ============
template<int BMODE, class TA, class TB, class TD, class TO>
__global__ __launch_bounds__(256) void gemm_t(
    const TA* __restrict__ A1, const TB* __restrict__ B1,
    const TA* __restrict__ A2, const TB* __restrict__ B2,
    const TD* __restrict__ D, TO* __restrict__ O,
    int M, int N, int Kp, int neg2, int act,
    long long sAb, long long sAm,
    long long sBb, long long sBr,
    long long sDb, long long sDm,
    long long sOb, long long sOm)
{
    __shared__ __align__(16) u16 As[64 * 32];
    __shared__ __align__(16) u16 Bs[BMODE ? 32 * 68 : 64 * 32];
    const int tid = threadIdx.x;
    const long long b = blockIdx.z;
    const int bm0 = blockIdx.y * 64;
    const int bn0 = blockIdx.x * 64;
    const int lane = tid & 63;
    const int wave = tid >> 6;
    const int wr = (wave >> 1) * 32;
    const int wc = (wave & 1) * 32;
    const int fr = lane & 15;
    const int fg = lane >> 4;
    const int arow = tid >> 2, achk = tid & 3;

    f32x4 acc[2][2];
#pragma unroll
    for (int i = 0; i < 2; ++i)
#pragma unroll
        for (int j = 0; j < 2; ++j) acc[i][j] = (f32x4){0.f, 0.f, 0.f, 0.f};

    const int nph = A2 ? 2 : 1;
    for (int ph = 0; ph < nph; ++ph) {
        const TA* Ap = (ph ? A2 : A1) + b * sAb;
        const TB* Bp = (ph ? B2 : B1) + b * sBb;
        const unsigned int sgn = (ph && neg2) ? 0x80008000u : 0u;
        for (int k0 = 0; k0 < Kp; k0 += 32) {
            uint4 av = load8(Ap + (long long)(bm0 + arow) * sAm + k0 + achk * 8);
            av.x ^= sgn; av.y ^= sgn; av.z ^= sgn; av.w ^= sgn;
            uint4 bv;
            if (BMODE == 0) {
                bv = load8(Bp + (long long)(bn0 + arow) * sBr + k0 + achk * 8);
            } else {
                const int bk = tid >> 3, bnc = tid & 7;
                bv = load8(Bp + (long long)(k0 + bk) * sBr + bn0 + bnc * 8);
            }
            __syncthreads();
            *(uint4*)(&As[arow * 32 + ((achk ^ ((arow >> 1) & 3)) * 8)]) = av;
            if (BMODE == 0) {
                *(uint4*)(&Bs[arow * 32 + ((achk ^ ((arow >> 1) & 3)) * 8)]) = bv;
            } else {
                const int bk = tid >> 3, bnc = tid & 7;
                *(uint2*)(&Bs[bk * 68 + bnc * 8]) = make_uint2(bv.x, bv.y);
                *(uint2*)(&Bs[bk * 68 + bnc * 8 + 4]) = make_uint2(bv.z, bv.w);
            }
            __syncthreads();
            short8v afrag[2], bfrag[2];
#pragma unroll
            for (int i = 0; i < 2; ++i) {
                int r = wr + i * 16 + fr;
                afrag[i] = *(const short8v*)(&As[r * 32 + ((fg ^ ((r >> 1) & 3)) * 8)]);
            }
            if (BMODE == 0) {
#pragma unroll
                for (int j = 0; j < 2; ++j) {
                    int r = wc + j * 16 + fr;
                    bfrag[j] = *(const short8v*)(&Bs[r * 32 + ((fg ^ ((r >> 1) & 3)) * 8)]);
                }
            } else {
#pragma unroll
                for (int j = 0; j < 2; ++j) {
                    int col = wc + j * 16 + fr;
                    short8v v;
#pragma unroll
                    for (int e = 0; e < 8; ++e) v[e] = (short)Bs[(fg * 8 + e) * 68 + col];
                    bfrag[j] = v;
                }
            }
#pragma unroll
            for (int i = 0; i < 2; ++i)
#pragma unroll
                for (int j = 0; j < 2; ++j)
                    acc[i][j] = __builtin_amdgcn_mfma_f32_16x16x32_bf16(afrag[i], bfrag[j], acc[i][j], 0, 0, 0);
        }
    }
#pragma unroll
    for (int i = 0; i < 2; ++i) {
#pragma unroll
        for (int j = 0; j < 2; ++j) {
            int col = bn0 + wc + j * 16 + fr;
            if (col >= N) continue;
#pragma unroll
            for (int r = 0; r < 4; ++r) {
                int row = bm0 + wr + i * 16 + fg * 4 + r;
                if (row >= M) continue;
                float v = acc[i][j][r];
                if (D) v += rdD(D + b * sDb + (long long)row * sDm + col);
                if (act) v = gelu_f(v);
                stO(O + b * sOb + (long long)row * sOm + col, v);
            }
        }
    }
}

// ============ XCD-pair-swizzled gemm_t<0>, batch=1 (R14-proven) ============
template<class TA, class TB, class TD, class TO>
__global__ __launch_bounds__(256) void gemm_ts(
    const TA* __restrict__ A, const TB* __restrict__ B,
    const TD* __restrict__ D, TO* __restrict__ O,
    int M, int N, int Kp, int act,
    long long sAm, long long sBr,
    long long sDm, long long sOm)
{
    __shared__ __align__(16) u16 As[64 * 32];
    __shared__ __align__(16) u16 Bs[64 * 32];
    const int tid = threadIdx.x;
    int lid = blockIdx.x + (int)gridDim.x * blockIdx.y;
    int total = (int)(gridDim.x * gridDim.y);
    int nx, ny;
    if ((lid & ~15) + 16 <= total) {
        nx = (lid >> 3) & 1;
        ny = ((lid >> 4) << 3) + (lid & 7);
    } else {
        nx = lid & 1;
        ny = lid >> 1;
    }
    const int bm0 = ny * 64;
    const int bn0 = nx * 64;
    const int lane = tid & 63;
    const int wave = tid >> 6;
    const int wr = (wave >> 1) * 32;
    const int wc = (wave & 1) * 32;
    const int fr = lane & 15;
    const int fg = lane >> 4;
    const int arow = tid >> 2, achk = tid & 3;
    const int aswz = (achk ^ ((arow >> 1) & 3)) * 8;

    f32x4 acc[2][2];
#pragma unroll
    for (int i = 0; i < 2; ++i)
#pragma unroll
        for (int j = 0; j < 2; ++j) acc[i][j] = (f32x4){0.f, 0.f, 0.f, 0.f};

    for (int k0 = 0; k0 < Kp; k0 += 32) {
        uint4 av = load8(A + (long long)(bm0 + arow) * sAm + k0 + achk * 8);
        uint4 bv = load8(B + (long long)(bn0 + arow) * sBr + k0 + achk * 8);
        __syncthreads();
        *(uint4*)(&As[arow * 32 + aswz]) = av;
        *(uint4*)(&Bs[arow * 32 + aswz]) = bv;
        __syncthreads();
        short8v afrag[2], bfrag[2];
#pragma unroll
        for (int i = 0; i < 2; ++i) {
            int r = wr + i * 16 + fr;
            afrag[i] = *(const short8v*)(&As[r * 32 + ((fg ^ ((r >> 1) & 3)) * 8)]);
        }
#pragma unroll
        for (int j = 0; j < 2; ++j) {
            int r = wc + j * 16 + fr;
            bfrag[j] = *(const short8v*)(&Bs[r * 32 + ((fg ^ ((r >> 1) & 3)) * 8)]);
        }
#pragma unroll
        for (int i = 0; i < 2; ++i)
#pragma unroll
            for (int j = 0; j < 2; ++j)
                acc[i][j] = __builtin_amdgcn_mfma_f32_16x16x32_bf16(afrag[i], bfrag[j], acc[i][j], 0, 0, 0);
    }
#pragma unroll
    for (int i = 0; i < 2; ++i) {
#pragma unroll
        for (int j = 0; j < 2; ++j) {
            int col = bn0 + wc + j * 16 + fr;
            if (col >= N) continue;
#pragma unroll
            for (int r = 0; r < 4; ++r) {
                int row = bm0 + wr + i * 16 + fg * 4 + r;
                if (row >= M) continue;
                float v = acc[i][j][r];
                if (D) v += rdD(D + (long long)row * sDm + col);
                if (act) v = gelu_f(v);
                stO(O + (long long)row * sOm + col, v);
            }
        }
    }
}

// ============ decoder GEMM: gemm_ts + fused x-skip + gelu epilogue ============
template<class TA, class TB>
__global__ __launch_bounds__(256) void gemm_dec(
    const TA* __restrict__ A, const TB* __restrict__ B, u16* __restrict__ O,
    int M, int Kp, long long sAm, long long sBr, long long sOm,
    const float* __restrict__ xin, const float* __restrict__ dw1, long long P)
{
    __shared__ __align__(16) u16 As[64 * 32];
    __shared__ __align__(16) u16 Bs[64 * 32];
    const int tid = threadIdx.x;
    int lid = blockIdx.x + (int)gridDim.x * blockIdx.y;
    int total = (int)(gridDim.x * gridDim.y);
    int nx, ny;
    if ((lid & ~15) + 16 <= total) {
        nx = (lid >> 3) & 1;
        ny = ((lid >> 4) << 3) + (lid & 7);
    } else {
        nx = lid & 1;
        ny = lid >> 1;
    }
    const int bm0 = ny * 64;
    const int bn0 = nx * 64;
    const int lane = tid & 63;
    const int wave = tid >> 6;
    const int wr = (wave >> 1) * 32;
    const int wc = (wave & 1) * 32;
    const int fr = lane & 15;
    const int fg = lane >> 4;
    const int arow = tid >> 2, achk = tid & 3;
    const int aswz = (achk ^ ((arow >> 1) & 3)) * 8;

    f32x4 acc[2][2];
#pragma unroll
    for (int i = 0; i < 2; ++i)
#pragma unroll
        for (int j = 0; j < 2; ++j) acc[i][j] = (f32x4){0.f, 0.f, 0.f, 0.f};

    for (int k0 = 0; k0 < Kp; k0 += 32) {
        uint4 av = load8(A + (long long)(bm0 + arow) * sAm + k0 + achk * 8);
        uint4 bv = load8(B + (long long)(bn0 + arow) * sBr + k0 + achk * 8);
        __syncthreads();
        *(uint4*)(&As[arow * 32 + aswz]) = av;
        *(uint4*)(&Bs[arow * 32 + aswz]) = bv;
        __syncthreads();
        short8v afrag[2], bfrag[2];
#pragma unroll
        for (int i = 0; i < 2; ++i) {
            int r = wr + i * 16 + fr;
            afrag[i] = *(const short8v*)(&As[r * 32 + ((fg ^ ((r >> 1) & 3)) * 8)]);
        }
#pragma unroll
        for (int j = 0; j < 2; ++j) {
            int r = wc + j * 16 + fr;
            bfrag[j] = *(const short8v*)(&Bs[r * 32 + ((fg ^ ((r >> 1) & 3)) * 8)]);
        }
#pragma unroll
        for (int i = 0; i < 2; ++i)
#pragma unroll
            for (int j = 0; j < 2; ++j)
                acc[i][j] = __builtin_amdgcn_mfma_f32_16x16x32_bf16(afrag[i], bfrag[j], acc[i][j], 0, 0, 0);
    }
#pragma unroll
    for (int j = 0; j < 2; ++j) {
        int col = bn0 + wc + j * 16 + fr;
        float w0 = dw1[col * 130 + 128];
        float w1 = dw1[col * 130 + 129];
#pragma unroll
        for (int i = 0; i < 2; ++i) {
#pragma unroll
            for (int r = 0; r < 4; ++r) {
                int row = bm0 + wr + i * 16 + fg * 4 + r;
                if (row >= M) continue;
                float v = bf2f(f2bf(acc[i][j][r]));   // keep stored-bf16 rounding
                float xv0 = xin[row], xv1 = xin[P + row];
                O[(long long)row * sOm + col] = f2bf(gelu_f(v + w0 * xv0 + w1 * xv1));
            }
        }
    }
}

// ============ decoder back (R5-proven): out = w2 . d1 (64-lane reduce) ============
__global__ __launch_bounds__(256) void dec_back(const u16* __restrict__ d1, const float* __restrict__ w2,
                                                float* __restrict__ out, long long P) {
    __shared__ float w2s[256];
    w2s[threadIdx.x] = w2[threadIdx.x];
    __syncthreads();
    int lane = threadIdx.x & 63;
    long long pix = (long long)blockIdx.x * 4 + (threadIdx.x >> 6);
    unsigned int pr = *(const unsigned int*)(d1 + pix * 128 + lane * 2);
    float b0 = bf2f((u16)(pr & 0xFFFF)), b1 = bf2f((u16)(pr >> 16));
    float s0 = b0 * w2s[lane * 2] + b1 * w2s[lane * 2 + 1];
    float s1 = b0 * w2s[128 + lane * 2] + b1 * w2s[128 + lane * 2 + 1];
#pragma unroll
    for (int off = 1; off < 64; off <<= 1) {
        s0 += __shfl_xor(s0, off);
        s1 += __shfl_xor(s1, off);
    }
    if (lane == 0) { out[pix] = s0; out[P + pix] = s1; }
}

// ============ fused MLP: O = m2 . gelu(m1 . A) + D ============
// Bit-exact vs the split pair (same f2bf rounding, same per-output k order
// 0..7). A tile held in REGISTERS (8 frags/thread, loaded directly from
// global with the same load8 conversion + element selection as the LDS
// round-trip -> identical values). LDS = 16 KB (Hs only): more blocks/CU,
// one fewer staging phase + barrier than R18's version (which was 209us,
// 31% achieved occupancy at l3).
template<class TA, class TD, class TO>
__global__ __launch_bounds__(256) void gemm_mlp(
    const TA* __restrict__ A, const u16* __restrict__ W1, const u16* __restrict__ W2,
    const TD* __restrict__ D, TO* __restrict__ O,
    int M, long long sAm, long long sDm, long long sOm)
{
    __shared__ __align__(16) u16 Hs[4][64 * 32];    // 16 KB: hidden half [64][128]
    const int tid = threadIdx.x;
    const int bm0 = blockIdx.x * 64;
    const int lane = tid & 63;
    const int wave = tid >> 6;
    const int wr = (wave >> 1) * 32;
    const int wc = (wave & 1) * 32;
    const int fr = lane & 15;
    const int fg = lane >> 4;

    // A fragments in registers: rows wr+i*16+fr, k-chunk kt*32+fg*8
    short8v afr[2][4];
#pragma unroll
    for (int i = 0; i < 2; ++i)
#pragma unroll
        for (int kt = 0; kt < 4; ++kt) {
            int r = bm0 + wr + i * 16 + fr;
            uint4 v = load8(A + (long long)r * sAm + kt * 32 + fg * 8);
            afr[i][kt] = *(short8v*)&v;
        }

    f32x4 acc2[2][2][2];
#pragma unroll
    for (int n2 = 0; n2 < 2; ++n2)
#pragma unroll
        for (int i = 0; i < 2; ++i)
#pragma unroll
            for (int j = 0; j < 2; ++j) acc2[n2][i][j] = (f32x4){0.f, 0.f, 0.f, 0.f};

#pragma unroll
    for (int half = 0; half < 2; ++half) {
        // phase 1: hidden cols [half*128, half*128+128)
#pragma unroll
        for (int nbi = 0; nbi < 2; ++nbi) {
            int nb = half * 2 + nbi;
            f32x4 acc[2][2];
#pragma unroll
            for (int i = 0; i < 2; ++i)
#pragma unroll
                for (int j = 0; j < 2; ++j) acc[i][j] = (f32x4){0.f, 0.f, 0.f, 0.f};
#pragma unroll
            for (int kt = 0; kt < 4; ++kt) {
                short8v bf[2];
#pragma unroll
                for (int j = 0; j < 2; ++j) {
                    int col = wc + nb * 64 + j * 16 + fr;
                    bf[j] = *(const short8v*)(W1 + (long long)col * 128 + kt * 32 + fg * 8);
                }
#pragma unroll
                for (int i = 0; i < 2; ++i)
#pragma unroll
                    for (int j = 0; j < 2; ++j)
                        acc[i][j] = __builtin_amdgcn_mfma_f32_16x16x32_bf16(afr[i][kt], bf[j], acc[i][j], 0, 0, 0);
            }
#pragma unroll
            for (int i = 0; i < 2; ++i)
#pragma unroll
                for (int j = 0; j < 2; ++j) {
                    int col = wc + nb * 64 + j * 16 + fr;
                    int kt2 = (col >> 5) & 3, kc = (col >> 3) & 3, ke = col & 7;
#pragma unroll
                    for (int r = 0; r < 4; ++r) {
                        int row = wr + i * 16 + fg * 4 + r;
                        Hs[kt2][row * 32 + ((kc ^ ((row >> 1) & 3)) * 8) + ke] = f2bf(gelu_f(acc[i][j][r]));
                    }
                }
        }
        __syncthreads();
        // phase 2 partial: global kt = half*4 + ktl, accumulates in order 0..7
#pragma unroll
        for (int n2 = 0; n2 < 2; ++n2) {
#pragma unroll
            for (int ktl = 0; ktl < 4; ++ktl) {
                short8v af[2], bf[2];
#pragma unroll
                for (int i = 0; i < 2; ++i) {
                    int r = wr + i * 16 + fr;
                    af[i] = *(const short8v*)(&Hs[ktl][r * 32 + ((fg ^ ((r >> 1) & 3)) * 8)]);
                }
#pragma unroll
                for (int j = 0; j < 2; ++j) {
                    int col = n2 * 64 + wc + j * 16 + fr;
                    bf[j] = *(const short8v*)(W2 + (long long)col * 256 + (half * 4 + ktl) * 32 + fg * 8);
                }
#pragma unroll
                for (int i = 0; i < 2; ++i)
#pragma unroll
                    for (int j = 0; j < 2; ++j)
                        acc2[n2][i][j] = __builtin_amdgcn_mfma_f32_16x16x32_bf16(af[i], bf[j], acc2[n2][i][j], 0, 0, 0);
            }
        }
        __syncthreads();
    }

#pragma unroll
    for (int n2 = 0; n2 < 2; ++n2) {
#pragma unroll
        for (int i = 0; i < 2; ++i) {
#pragma unroll
            for (int j = 0; j < 2; ++j) {
                int col = n2 * 64 + wc + j * 16 + fr;
#pragma unroll
                for (int r = 0; r < 4; ++r) {
                    int row = bm0 + wr + i * 16 + fg * 4 + r;
                    if (row >= M) continue;
                    float v = acc2[n2][i][j][r];
                    if (D) v += rdD(D + (long long)row * sDm + col);
                    stO(O + (long long)row * sOm + col, v);
                }
            }
        }
    }
}

// ============ fused dual-output MFMA GEMM (derived from gemm_t) ============
template<int BMODE, int MODE, class TA, class TB, class TO>
__global__ __launch_bounds__(256) void gemm_t2(
    const TA* __restrict__ A1, const TA* __restrict__ A2,
    const TB* __restrict__ B1, const TB* __restrict__ B2,
    TO* __restrict__ O1, TO* __restrict__ O2,
    int M, int N, int Kp, int s2neg,
    long long sAb, long long sAm,
    long long sBb, long long sBr,
    long long sOb, long long sOm)
{
    __shared__ __align__(16) u16 As1[64 * 32], As2[64 * 32];
    __shared__ __align__(16) u16 Bs1[BMODE ? 32 * 68 : 64 * 32];
    __shared__ __align__(16) u16 Bs2[(MODE == 1) ? 16 : (BMODE ? 32 * 68 : 64 * 32)];
    const int tid = threadIdx.x;
    const long long b = blockIdx.z;
    const int bm0 = blockIdx.y * 64;
    const int bn0 = blockIdx.x * 64;
    const int lane = tid & 63;
    const int wave = tid >> 6;
    const int wr = (wave >> 1) * 32;
    const int wc = (wave & 1) * 32;
    const int fr = lane & 15;
    const int fg = lane >> 4;
    const int arow = tid >> 2, achk = tid & 3;
    const int aswz = (achk ^ ((arow >> 1) & 3)) * 8;

    f32x4 acc1[2][2], acc2[2][2];
#pragma unroll
    for (int i = 0; i < 2; ++i)
#pragma unroll
        for (int j = 0; j < 2; ++j) {
            acc1[i][j] = (f32x4){0.f, 0.f, 0.f, 0.f};
            acc2[i][j] = (f32x4){0.f, 0.f, 0.f, 0.f};
        }

    const TA* A1b = A1 + b * sAb;
    const TA* A2b = A2 + b * sAb;
    const TB* B1b = B1 + b * sBb;
    const TB* B2b = (MODE == 0) ? B2 + b * sBb : B1;

    for (int k0 = 0; k0 < Kp; k0 += 32) {
        long long aoff = (long long)(bm0 + arow) * sAm + k0 + achk * 8;
        uint4 av1 = load8(A1b + aoff);
        uint4 av2 = load8(A2b + aoff);
        uint4 bv1, bv2;
        if (BMODE == 0) {
            long long boff = (long long)(bn0 + arow) * sBr + k0 + achk * 8;
            bv1 = load8(B1b + boff);
            if (MODE == 0) bv2 = load8(B2b + boff);
        } else {
            const int bk = tid >> 3, bnc = tid & 7;
            long long boff = (long long)(k0 + bk) * sBr + bn0 + bnc * 8;
            bv1 = load8(B1b + boff);
            if (MODE == 0) bv2 = load8(B2b + boff);
        }
        __syncthreads();
        *(uint4*)(&As1[arow * 32 + aswz]) = av1;
        *(uint4*)(&As2[arow * 32 + aswz]) = av2;
        if (BMODE == 0) {
            *(uint4*)(&Bs1[arow * 32 + aswz]) = bv1;
            if (MODE == 0) *(uint4*)(&Bs2[arow * 32 + aswz]) = bv2;
        } else {
            const int bk = tid >> 3, bnc = tid & 7;
            *(uint2*)(&Bs1[bk * 68 + bnc * 8]) = make_uint2(bv1.x, bv1.y);
            *(uint2*)(&Bs1[bk * 68 + bnc * 8 + 4]) = make_uint2(bv1.z, bv1.w);
            if (MODE == 0) {
                *(uint2*)(&Bs2[bk * 68 + bnc * 8]) = make_uint2(bv2.x, bv2.y);
                *(uint2*)(&Bs2[bk * 68 + bnc * 8 + 4]) = make_uint2(bv2.z, bv2.w);
            }
        }
        __syncthreads();
        short8v a1f[2], a2f[2], b1f[2], b2f[2];
#pragma unroll
        for (int i = 0; i < 2; ++i) {
            int r = wr + i * 16 + fr;
            int o = r * 32 + ((fg ^ ((r >> 1) & 3)) * 8);
            a1f[i] = *(const short8v*)(&As1[o]);
            a2f[i] = *(const short8v*)(&As2[o]);
        }
        if (BMODE == 0) {
#pragma unroll
            for (int j = 0; j < 2; ++j) {
                int r = wc + j * 16 + fr;
                int o = r * 32 + ((fg ^ ((r >> 1) & 3)) * 8);
                b1f[j] = *(const short8v*)(&Bs1[o]);
                if (MODE == 0) b2f[j] = *(const short8v*)(&Bs2[o]);
            }
        } else {
#pragma unroll
            for (int j = 0; j < 2; ++j) {
                int col = wc + j * 16 + fr;
                short8v v1, v2;
#pragma unroll
                for (int e = 0; e < 8; ++e) {
                    v1[e] = (short)Bs1[(fg * 8 + e) * 68 + col];
                    if (MODE == 0) v2[e] = (short)Bs2[(fg * 8 + e) * 68 + col];
                }
                b1f[j] = v1;
                if (MODE == 0) b2f[j] = v2;
            }
        }
        if (MODE == 1) {
#pragma unroll
            for (int i = 0; i < 2; ++i)
#pragma unroll
                for (int j = 0; j < 2; ++j) {
                    acc1[i][j] = __builtin_amdgcn_mfma_f32_16x16x32_bf16(a1f[i], b1f[j], acc1[i][j], 0, 0, 0);
                    acc2[i][j] = __builtin_amdgcn_mfma_f32_16x16x32_bf16(a2f[i], b1f[j], acc2[i][j], 0, 0, 0);
                }
        } else {
            short8v a2p[2], a2m[2];
#pragma unroll
            for (int i = 0; i < 2; ++i) {
                a2p[i] = s2neg ? negbf(a2f[i]) : a2f[i];
                a2m[i] = s2neg ? a2f[i] : negbf(a2f[i]);
            }
#pragma unroll
            for (int i = 0; i < 2; ++i)
#pragma unroll
                for (int j = 0; j < 2; ++j) {
                    acc1[i][j] = __builtin_amdgcn_mfma_f32_16x16x32_bf16(a1f[i], b1f[j], acc1[i][j], 0, 0, 0);
                    acc1[i][j] = __builtin_amdgcn_mfma_f32_16x16x32_bf16(a2p[i], b2f[j], acc1[i][j], 0, 0, 0);
                    acc2[i][j] = __builtin_amdgcn_mfma_f32_16x16x32_bf16(a1f[i], b2f[j], acc2[i][j], 0, 0, 0);
                    acc2[i][j] = __builtin_amdgcn_mfma_f32_16x16x32_bf16(a2m[i], b1f[j], acc2[i][j], 0, 0, 0);
                }
        }
    }
#pragma unroll
    for (int i = 0; i < 2; ++i) {
#pragma unroll
        for (int j = 0; j < 2; ++j) {
            int col = bn0 + wc + j * 16 + fr;
            if (col >= N) continue;
#pragma unroll
            for (int r = 0; r < 4; ++r) {
                int row = bm0 + wr + i * 16 + fg * 4 + r;
                if (row >= M) continue;
                long long oi = b * sOb + (long long)row * sOm + col;
                stO(O1 + oi, acc1[i][j][r]);
                stO(O2 + oi, acc2[i][j][r]);
            }
        }
    }
}

// ============ DFT matrix generators (bf16, zero-padded) ============
__global__ void gen_fwdW_T(u16* Cm, u16* Sm, int RP, int KP, int W, int MM) {
    int idx = blockIdx.x * blockDim.x + threadIdx.x;
    if (idx >= RP * KP) return;
    int m = idx / KP, w = idx % KP;
    float cv = 0.f, sv = 0.f;
    if (m < MM && w < W) {
        int t = (m * w) % W;
        float arg = 2.0f * (float)t / (float)W;
        float s = 1.0f / sqrtf((float)W);
        cv = cospif(arg) * s; sv = -sinpif(arg) * s;
    }
    Cm[idx] = f2bf(cv); Sm[idx] = f2bf(sv);
}
__global__ void gen_fwdH(u16* Cm, u16* Sm, int RP, int KP, int H) {
    int idx = blockIdx.x * blockDim.x + threadIdx.x;
    if (idx >= RP * KP) return;
    int l = idx / KP, h = idx % KP;
    float cv = 0.f, sv = 0.f;
    if (l < 90 && h < H) {
        int ll = (l < 45) ? l : l + H - 90;
        int t = (ll * h) % H;
        float arg = 2.0f * (float)t / (float)H;
        float s = 1.0f / sqrtf((float)H);
        cv = cospif(arg) * s; sv = sinpif(arg) * s;
    }
    Cm[idx] = f2bf(cv); Sm[idx] = f2bf(sv);
}
__global__ void gen_invH(u16* Cm, u16* Sm, int RP, int KP, int H) {
    int idx = blockIdx.x * blockDim.x + threadIdx.x;
    if (idx >= RP * KP) return;
    int y = idx / KP, l = idx % KP;
    float cv = 0.f, sv = 0.f;
    if (y < H && l < 90) {
        int ll = (l < 45) ? l : l + H - 90;
        int t = (ll * y) % H;
        float arg = 2.0f * (float)t / (float)H;
        float s = 1.0f / sqrtf((float)H);
        cv = cospif(arg) * s; sv = sinpif(arg) * s;
    }
    Cm[idx] = f2bf(cv); Sm[idx] = f2bf(sv);
}
__global__ void gen_invW_T(u16* Cm, u16* Sm, int RP, int KP, int W, int MM) {
    int idx = blockIdx.x * blockDim.x + threadIdx.x;
    if (idx >= RP * KP) return;
    int w = idx / KP, m = idx % KP;
    float cv = 0.f, sv = 0.f;
    if (w < W && m < MM) {
        int t = (m * w) % W;
        float arg = 2.0f * (float)t / (float)W;
        bool nyq = (2 * m == W);
        float wt = (m == 0 || nyq) ? 1.0f : 2.0f;
        float s = wt / sqrtf((float)W);
        cv = cospif(arg) * s;
        sv = nyq ? 0.f : sinpif(arg) * s;
    }
    Cm[idx] = f2bf(cv); Sm[idx] = f2bf(sv);
}

// ============ weight prep ============
__global__ void w2bf(const float* __restrict__ in, u16* __restrict__ out, int R, int K, int rs) {
    int idx = blockIdx.x * blockDim.x + threadIdx.x;
    if (idx >= R * K) return;
    int r = idx / K, c = idx % K;
    out[idx] = f2bf(in[(long long)r * rs + c]);
}
__global__ void transp_sw(const float* __restrict__ in, u16* __restrict__ out) {
    __shared__ float t[32][33];
    int l0 = blockIdx.x * 32, ci0 = blockIdx.y * 32, co = blockIdx.z;
    int tx = threadIdx.x, ty = threadIdx.y;
#pragma unroll
    for (int rr = 0; rr < 4; ++rr) {
        int ci = ci0 + ty + rr * 8;
        int l = l0 + tx;
        t[ty + rr * 8][tx] = (l < 90) ? in[((long long)ci * 128 + co) * 90 + l] : 0.f;
    }
    __syncthreads();
#pragma unroll
    for (int rr = 0; rr < 4; ++rr) {
        int l = l0 + ty + rr * 8;
        int ci = ci0 + tx;
        if (l < 90) out[((long long)l * 128 + co) * 128 + ci] = f2bf(t[tx][ty + rr * 8]);
    }
}

// ============ instance norm ============
__global__ __launch_bounds__(256) void stats_cl_bf(const u16* __restrict__ x, long long P,
                                                   float2* __restrict__ part, int nch) {
    int chunk = blockIdx.x;
    int c = threadIdx.x & 127;
    int h = threadIdx.x >> 7;
    long long beg = P * chunk / nch, end = P * (chunk + 1) / nch;
    float s = 0.f, q = 0.f;
    long long p = beg + h;
    for (; p + 14 < end; p += 16) {
        float v[8];
#pragma unroll
        for (int u = 0; u < 8; ++u) v[u] = bf2f(x[(p + 2 * u) * 128 + c]);
#pragma unroll
        for (int u = 0; u < 8; ++u) { s += v[u]; q += v[u] * v[u]; }
    }
    for (; p < end; p += 2) {
        float v = bf2f(x[p * 128 + c]);
        s += v; q += v * v;
    }
    __shared__ float rs[256], rq[256];
    rs[threadIdx.x] = s; rq[threadIdx.x] = q;
    __syncthreads();
    if (threadIdx.x < 128)
        part[(long long)c * nch + chunk] = make_float2(rs[c] + rs[c + 128], rq[c] + rq[c + 128]);
}
__global__ __launch_bounds__(256) void stats_cl_f32(const float* __restrict__ x, long long P,
                                                    float2* __restrict__ part, int nch) {
    int chunk = blockIdx.x;
    long long beg = P * chunk / nch, end = P * (chunk + 1) / nch;
    int c32 = threadIdx.x & 31;
    int pr  = threadIdx.x >> 5;
    float s[4], q[4];
#pragma unroll
    for (int k = 0; k < 4; ++k) { s[k] = 0.f; q[k] = 0.f; }
    for (long long p = beg + pr; p < end; p += 8) {
        float4 v = *(const float4*)(x + p * 128 + c32 * 4);
        float e[4] = {v.x, v.y, v.z, v.w};
#pragma unroll
        for (int k = 0; k < 4; ++k) { s[k] += e[k]; q[k] += e[k] * e[k]; }
    }
#pragma unroll
    for (int k = 0; k < 4; ++k) {
        s[k] += __shfl_xor(s[k], 32); q[k] += __shfl_xor(q[k], 32);
    }
    __shared__ float2 lds[4][128];
    int wv = threadIdx.x >> 6, lane = threadIdx.x & 63;
    if (lane < 32) {
#pragma unroll
        for (int k = 0; k < 4; ++k) lds[wv][lane * 4 + k] = make_float2(s[k], q[k]);
    }
    __syncthreads();
    if (threadIdx.x < 128) {
        float2 a = lds[0][threadIdx.x], b2 = lds[1][threadIdx.x];
        float2 c2 = lds[2][threadIdx.x], d2 = lds[3][threadIdx.x];
        part[(long long)threadIdx.x * nch + chunk] =
            make_float2(a.x + b2.x + c2.x + d2.x, a.y + b2.y + c2.y + d2.y);
    }
}
__global__ void stats_fin(const float2* __restrict__ part, int nch, float Pf,
                          const float* __restrict__ w, const float* __restrict__ b,
                          float2* __restrict__ st) {
    int c = threadIdx.x;
    float s = 0.f, q = 0.f;
    for (int i = 0; i < nch; ++i) { float2 p = part[(long long)c * nch + i]; s += p.x; q += p.y; }
    float mu = s / Pf;
    float var = q / Pf - mu * mu;
    float inv = rsqrtf(var + 1e-5f);
    float sc = w[c] * inv;
    st[c] = make_float2(sc, b[c] - mu * sc);
}
__global__ __launch_bounds__(256) void norm_apply_bf(const u16* __restrict__ src, u16* __restrict__ dst,
                                                     long long n8, const float2* __restrict__ st) {
    long long i = (long long)blockIdx.x * 256 + threadIdx.x;
    if (i >= n8) return;
    int c0 = (int)((i * 8) & 127);
    uint4 v = *(const uint4*)(src + i * 8);
    union { uint4 u; u16 e[8]; } in, out;
    in.u = v;
#pragma unroll
    for (int k = 0; k < 8; ++k) {
        float2 s = st[c0 + k];
        out.e[k] = f2bf(bf2f(in.e[k]) * s.x + s.y);
    }
    *(uint4*)(dst + i * 8) = out.u;
}
__global__ __launch_bounds__(256) void norm_apply_f32(const float4* __restrict__ src, float4* __restrict__ dst,
                                                      long long n4, const float2* __restrict__ st) {
    long long i = (long long)blockIdx.x * 256 + threadIdx.x;
    if (i >= n4) return;
    int c0 = (int)((i * 4) & 127);
    float4 v = src[i];
    float2 s0 = st[c0], s1 = st[c0 + 1], s2 = st[c0 + 2], s3 = st[c0 + 3];
    v.x = v.x * s0.x + s0.y;
    v.y = v.y * s1.x + s1.y;
    v.z = v.z * s2.x + s2.y;
    v.w = v.w * s3.x + s3.y;
    dst[i] = v;
}

// ============ encoder front ============
__global__ __launch_bounds__(256) void enc_front(const float* __restrict__ x, const float* __restrict__ w1,
                                                 u16* __restrict__ out, long long P) {
    long long idx = (long long)blockIdx.x * 256 + threadIdx.x;
    if (idx >= P * 16) return;
    long long p = idx >> 4;
    int c0 = (int)(idx & 15) * 8;
    float x0 = x[p], x1 = x[P + p];
    union { uint4 u; u16 e[8]; } o;
#pragma unroll
    for (int k = 0; k < 8; ++k) {
        int c = c0 + k;
        o.e[k] = f2bf(gelu_f(w1[c * 2] * x0 + w1[c * 2 + 1] * x1));
    }
    *(uint4*)(out + p * 128 + c0) = o.u;
}

__global__ void zero_out(float* p, long long n) {
    long long i = (long long)blockIdx.x * 256 + threadIdx.x;
    if (i < n) p[i] = 0.f;
}

// ============ host ============
extern "C" void kernel_launch(void* const* d_in, const int* in_sizes, int n_in,
                              void* d_out, int out_size, void* d_ws, size_t ws_size,
                              hipStream_t stream)
{
    const int HF = 360, WF = 720, HL = 90, WL = 180, C = 128, MM = 91;
    const long long PF = (long long)HF * WF;
    const long long PL = (long long)HL * WL;
    (void)in_sizes; (void)n_in;

    const float* x      = (const float*)d_in[0];
    const float* enc_w1 = (const float*)d_in[1];
    const float* enc_w2 = (const float*)d_in[2];
    const float* n0w    = (const float*)d_in[3];
    const float* n0b    = (const float*)d_in[4];
    const float* swr    = (const float*)d_in[5];
    const float* swi    = (const float*)d_in[6];
    const float* iw     = (const float*)d_in[7];
    const float* n1w    = (const float*)d_in[8];
    const float* n1b    = (const float*)d_in[9];
    const float* mw1    = (const float*)d_in[10];
    const float* mw2    = (const float*)d_in[11];
    const float* dec_w1 = (const float*)d_in[12];
    const float* dec_w2 = (const float*)d_in[13];
    float* outp = (float*)d_out;

    u16* ws = (u16*)d_ws;
    long long off = 0;
    auto alloc = [&](long long n) { u16* p = ws + off; off += (n + 31) & ~31LL; return p; };
    auto allocF = [&](long long n) { return (float*)alloc(2 * n); };

    u16*   FULL = alloc(PF * C);
    u16*   RES  = alloc(PF * C);
    u16*   S1r  = alloc(96LL * 384 * 128);
    u16*   S1i  = alloc(96LL * 384 * 128);
    float* Xr   = allocF(96LL * 96 * 128);
    float* Xi   = allocF(96LL * 96 * 128);
    float* Yr   = allocF(96LL * 96 * 128);
    float* Yi   = allocF(96LL * 96 * 128);
    u16*   G1r  = alloc(360LL * 96 * 128);
    u16*   G1i  = alloc(360LL * 96 * 128);
    u16*   G3r  = alloc(360LL * 96 * 128);
    u16*   G3i  = alloc(360LL * 96 * 128);
    float* Rlo  = allocF(PL * C);
    float* L0   = allocF(PL * C);
    u16*   WtR  = alloc(90LL * 128 * 128);
    u16*   WtI  = alloc(90LL * 128 * 128);
    u16* encw2b = alloc(128 * 128);
    u16* iwb    = alloc(128 * 128);
    u16* m1b    = alloc(256 * 128);
    u16* m2b    = alloc(128 * 256);
    u16* dw1b   = alloc(128 * 128);
    u16* CwTc_h = alloc(128 * 736); u16* CwTs_h = alloc(128 * 736);
    u16* CwTc_l = alloc(128 * 192); u16* CwTs_l = alloc(128 * 192);
    u16* Chc_h  = alloc(128 * 384); u16* Chs_h  = alloc(128 * 384);
    u16* Chc_l  = alloc(128 * 96);  u16* Chs_l  = alloc(128 * 96);
    u16* C2c_h  = alloc(384 * 96);  u16* C2s_h  = alloc(384 * 96);
    u16* C2c_l  = alloc(128 * 96);  u16* C2s_l  = alloc(128 * 96);
    u16* CwIc_h = alloc(768 * 96);  u16* CwIs_h = alloc(768 * 96);
    u16* CwIc_l = alloc(192 * 96);  u16* CwIs_l = alloc(192 * 96);
    float2* PART = (float2*)alloc(128 * 256 * 4);
    float2* STb  = (float2*)alloc(128 * 4);
    alloc(64 * 1024);   // slack for staged over-reads

    if ((size_t)(off * 2) > ws_size) {
        zero_out<<<(int)((out_size + 255) / 256), 256, 0, stream>>>(outp, out_size);
        return;
    }

    auto grid3 = [](int M, int N, int batch) {
        return dim3((unsigned)((N + 63) / 64), (unsigned)((M + 63) / 64), (unsigned)batch);
    };
    auto inormB = [&](const u16* src, u16* dst, long long P, int nch,
                      const float* w, const float* b) {
        stats_cl_bf<<<nch, 256, 0, stream>>>(src, P, PART, nch);
        stats_fin<<<1, 128, 0, stream>>>(PART, nch, (float)P, w, b, STb);
        long long n8 = P * 128 / 8;
        norm_apply_bf<<<(int)((n8 + 255) / 256), 256, 0, stream>>>(src, dst, n8, STb);
    };
    auto inormF = [&](const float* src, float* dst, long long P, int nch,
                      const float* w, const float* b) {
        stats_cl_f32<<<nch, 256, 0, stream>>>(src, P, PART, nch);
        stats_fin<<<1, 128, 0, stream>>>(PART, nch, (float)P, w, b, STb);
        long long n4 = P * 128 / 4;
        norm_apply_f32<<<(int)((n4 + 255) / 256), 256, 0, stream>>>(
            (const float4*)src, (float4*)dst, n4, STb);
    };

    const u16* nullU = nullptr;
    const float* nullF = nullptr;

    // ---- DFT matrices ----
    {
        int n;
        n = 128 * 736; gen_fwdW_T<<<(n + 255) / 256, 256, 0, stream>>>(CwTc_h, CwTs_h, 128, 736, 720, MM);
        n = 128 * 192; gen_fwdW_T<<<(n + 255) / 256, 256, 0, stream>>>(CwTc_l, CwTs_l, 128, 192, 180, MM);
        n = 128 * 384; gen_fwdH<<<(n + 255) / 256, 256, 0, stream>>>(Chc_h, Chs_h, 128, 384, 360);
        n = 128 * 96;  gen_fwdH<<<(n + 255) / 256, 256, 0, stream>>>(Chc_l, Chs_l, 128, 96, 90);
        n = 384 * 96;  gen_invH<<<(n + 255) / 256, 256, 0, stream>>>(C2c_h, C2s_h, 384, 96, 360);
        n = 128 * 96;  gen_invH<<<(n + 255) / 256, 256, 0, stream>>>(C2c_l, C2s_l, 128, 96, 90);
        n = 768 * 96;  gen_invW_T<<<(n + 255) / 256, 256, 0, stream>>>(CwIc_h, CwIs_h, 768, 96, 720, MM);
        n = 192 * 96;  gen_invW_T<<<(n + 255) / 256, 256, 0, stream>>>(CwIc_l, CwIs_l, 192, 96, 180, MM);
        n = 128 * 128; w2bf<<<(n + 255) / 256, 256, 0, stream>>>(enc_w2, encw2b, 128, 128, 128);
        n = 128 * 128; w2bf<<<(n + 255) / 256, 256, 0, stream>>>(dec_w1, dw1b, 128, 128, 130);
    }

    // ---- encoder ----
    enc_front<<<(int)((PF * 16 + 255) / 256), 256, 0, stream>>>(x, enc_w1, RES, PF);
    gemm_ts<u16, u16, u16, u16><<<grid3((int)PF, 128, 1), 256, 0, stream>>>(
        RES, encw2b, nullU, FULL, (int)PF, 128, 128, 0, 128, 128, 0, 128);

    const long long s96 = 96LL * 128;

    for (int l = 0; l < 4; ++l) {
        const bool inHi = (l == 0), outHi = (l == 3);
        const int Hin = inHi ? HF : HL, Win = inHi ? WF : WL;
        const int Hout = outHi ? HF : HL, Wout = outHi ? WF : WL;
        const long long Pout = (long long)Hout * Wout;
        const int hdim = inHi ? 384 : 96;
        const int Wp = inHi ? 736 : 192;
        const int hp = inHi ? 384 : 96;
        const u16* CwTc = inHi ? CwTc_h : CwTc_l;  const u16* CwTs = inHi ? CwTs_h : CwTs_l;
        const u16* Chc  = inHi ? Chc_h  : Chc_l;   const u16* Chs  = inHi ? Chs_h  : Chs_l;
        const u16* C2c  = outHi ? C2c_h : C2c_l;   const u16* C2s  = outHi ? C2s_h : C2s_l;
        const u16* CwIc = outHi ? CwIc_h : CwIc_l; const u16* CwIs = outHi ? CwIs_h : CwIs_l;

        {
            dim3 gt(3, 4, 128); dim3 bt(32, 8);
            transp_sw<<<gt, bt, 0, stream>>>(swr + (long long)l * C * C * 90, WtR);
            transp_sw<<<gt, bt, 0, stream>>>(swi + (long long)l * C * C * 90, WtI);
            int n = 128 * 128; w2bf<<<(n + 255) / 256, 256, 0, stream>>>(iw + (long long)l * C * C, iwb, 128, 128, 128);
            n = 256 * 128; w2bf<<<(n + 255) / 256, 256, 0, stream>>>(mw1 + (long long)l * 256 * C, m1b, 256, 128, 128);
            n = 128 * 256; w2bf<<<(n + 255) / 256, 256, 0, stream>>>(mw2 + (long long)l * C * 256, m2b, 128, 256, 256);
        }

        if (inHi) {
            inormB(FULL, RES, PF, 256, n0w + l * C, n0b + l * C);
            gemm_t2<1, 1, u16, u16, u16><<<grid3(96, 128, Hin), 256, 0, stream>>>(
                CwTc, CwTs, RES, nullU, S1r, S1i, 96, 128, Wp, 0,
                0, Wp, (long long)Win * 128, 128, 128, (long long)hdim * 128);
        } else {
            inormF(Rlo, L0, PL, 128, n0w + l * C, n0b + l * C);
            gemm_t2<1, 1, u16, float, u16><<<grid3(96, 128, Hin), 256, 0, stream>>>(
                CwTc, CwTs, L0, nullF, S1r, S1i, 96, 128, Wp, 0,
                0, Wp, (long long)Win * 128, 128, 128, (long long)hdim * 128);
        }

        gemm_t2<1, 0, u16, u16, float><<<grid3(96, 128, 96), 256, 0, stream>>>(
            Chc, Chs, S1r, S1i, Xr, Xi, 96, 128, hp, 0,
            0, hp, (long long)hdim * 128, 128, 128, s96);

        if (inHi || outHi) {
            gemm_t2<1, 0, u16, float, u16><<<grid3(Hout, 128, 96), 256, 0, stream>>>(
                C2c, C2s, Xr, Xi, G3r, G3i, Hout, 128, 96, 1,
                0, 96, 128, s96, 128, s96);
        }

        gemm_t2<0, 0, float, u16, float><<<grid3(96, 128, 90), 256, 0, stream>>>(
            Xr, Xi, WtR, WtI, Yr, Yi, 96, 128, 128, 1,
            s96, 128, 128LL * 128, 128, 128, s96);

        gemm_t2<1, 0, u16, float, u16><<<grid3(Hout, 128, 96), 256, 0, stream>>>(
            C2c, C2s, Yr, Yi, G1r, G1i, Hout, 128, 96, 1,
            0, 96, s96, 128, 128, s96);

        if (!outHi) {
            gemm_t<1, u16, u16, u16, float><<<grid3(Wout, 128, Hout), 256, 0, stream>>>(
                CwIc, G1r, CwIs, G1i, nullU, Rlo, Wout, 128, 96, 1, 0,
                0, 96, s96, 128, 0, 0, (long long)Wout * 128, 128);
            if (inHi)
                gemm_t<1, u16, u16, u16, float><<<grid3(Wout, 128, Hout), 256, 0, stream>>>(
                    CwIc, G3r, CwIs, G3i, nullU, L0, Wout, 128, 96, 1, 0,
                    0, 96, s96, 128, 0, 0, (long long)Wout * 128, 128);
            gemm_t<0, float, u16, float, float><<<grid3((int)Pout, 128, 1), 256, 0, stream>>>(
                L0, iwb, nullF, nullU, Rlo, Rlo, (int)Pout, 128, 128, 0, 1,
                0, 128, 0, 128, 0, 128, 0, 128);
            inormF(Rlo, Rlo, Pout, 128, n1w + l * C, n1b + l * C);
            gemm_mlp<float, float, float><<<dim3((unsigned)((Pout + 63) / 64)), 256, 0, stream>>>(
                Rlo, m1b, m2b, L0, Rlo, (int)Pout, 128, 128, 128);
        } else {
            gemm_t<1, u16, u16, u16, u16><<<grid3(Wout, 128, Hout), 256, 0, stream>>>(
                CwIc, G1r, CwIs, G1i, nullU, FULL, Wout, 128, 96, 1, 0,
                0, 96, s96, 128, 0, 0, (long long)Wout * 128, 128);
            gemm_t<1, u16, u16, u16, u16><<<grid3(Wout, 128, Hout), 256, 0, stream>>>(
                CwIc, G3r, CwIs, G3i, nullU, RES, Wout, 128, 96, 1, 0,
                0, 96, s96, 128, 0, 0, (long long)Wout * 128, 128);
            gemm_ts<u16, u16, u16, u16><<<grid3((int)Pout, 128, 1), 256, 0, stream>>>(
                RES, iwb, FULL, FULL, (int)Pout, 128, 128, 1, 128, 128, 128, 128);
            inormB(FULL, FULL, Pout, 256, n1w + l * C, n1b + l * C);
            gemm_mlp<u16, u16, u16><<<dim3((unsigned)((Pout + 63) / 64)), 256, 0, stream>>>(
                FULL, m1b, m2b, RES, FULL, (int)Pout, 128, 128, 128);
        }
    }

    // ---- decoder: GEMM with fused x-skip+gelu epilogue, then reduce ----
    gemm_dec<u16, u16><<<grid3((int)PF, 128, 1), 256, 0, stream>>>(
        FULL, dw1b, RES, (int)PF, 128, 128, 128, 128, x, dec_w1, PF);
    dec_back<<<(int)(PF / 4), 256, 0, stream>>>(RES, dec_w2, outp, PF);
}

// Round 20
// 1234.416 us; speedup vs baseline: 1.0188x; 1.0188x over previous
//
#include <hip/hip_runtime.h>
#include <hip/hip_bf16.h>
#include <math.h>

typedef __attribute__((ext_vector_type(8))) short short8v;
typedef __attribute__((ext_vector_type(4))) float f32x4;
typedef unsigned short u16;

__device__ __forceinline__ float gelu_f(float x) {
    return 0.5f * x * (1.0f + erff(x * 0.70710678118654752f));
}
__device__ __forceinline__ float bf2f(u16 u) {
    union { unsigned int i; float f; } v; v.i = ((unsigned int)u) << 16; return v.f;
}
__device__ __forceinline__ u16 f2bf(float f) {
    union { float f; unsigned int i; } v; v.f = f;
    unsigned int r = v.i + 0x7FFFu + ((v.i >> 16) & 1u);
    return (u16)(r >> 16);
}
__device__ __forceinline__ short8v negbf(short8v a) {
    uint4 u = *(uint4*)&a;
    u.x ^= 0x80008000u; u.y ^= 0x80008000u; u.z ^= 0x80008000u; u.w ^= 0x80008000u;
    return *(short8v*)&u;
}

// ---- typed 8-element (as packed bf16) loads, D reads, O stores ----
__device__ __forceinline__ uint4 load8(const u16* p) { return *(const uint4*)p; }
__device__ __forceinline__ uint4 load8(const float* p) {
    float4 a = *(const float4*)p;
    float4 b = *(const float4*)(p + 4);
    union { uint4 u; u16 e[8]; } r;
    r.e[0] = f2bf(a.x); r.e[1] = f2bf(a.y); r.e[2] = f2bf(a.z); r.e[3] = f2bf(a.w);
    r.e[4] = f2bf(b.x); r.e[5] = f2bf(b.y); r.e[6] = f2bf(b.z); r.e[7] = f2bf(b.w);
    return r.u;
}
__device__ __forceinline__ float rdD(const u16* p) { return bf2f(*p); }
__device__ __forceinline__ float rdD(const float* p) { return *p; }
__device__ __forceinline__ void stO(u16* p, float v) { *p = f2bf(v); }
__device__ __forceinline__ void stO(float* p, float v) { *p = v; }

// ============ typed MFMA GEMM (R5-proven structure, 64x64 tile) ============
template<int BMODE, class TA, class TB, class TD, class TO>
__global__ __launch_bounds__(256) void gemm_t(
    const TA* __restrict__ A1, const TB* __restrict__ B1,
    const TA* __restrict__ A2, const TB* __restrict__ B2,
    const TD* __restrict__ D, TO* __restrict__ O,
    int M, int N, int Kp, int neg2, int act,
    long long sAb, long long sAm,
    long long sBb, long long sBr,
    long long sDb, long long sDm,
    long long sOb, long long sOm)
{
    __shared__ __align__(16) u16 As[64 * 32];
    __shared__ __align__(16) u16 Bs[BMODE ? 32 * 68 : 64 * 32];
    const int tid = threadIdx.x;
    const long long b = blockIdx.z;
    const int bm0 = blockIdx.y * 64;
    const int bn0 = blockIdx.x * 64;
    const int lane = tid & 63;
    const int wave = tid >> 6;
    const int wr = (wave >> 1) * 32;
    const int wc = (wave & 1) * 32;
    const int fr = lane & 15;
    const int fg = lane >> 4;
    const int arow = tid >> 2, achk = tid & 3;

    f32x4 acc[2][2];
#pragma unroll
    for (int i = 0; i < 2; ++i)
#pragma unroll
        for (int j = 0; j < 2; ++j) acc[i][j] = (f32x4){0.f, 0.f, 0.f, 0.f};

    const int nph = A2 ? 2 : 1;
    for (int ph = 0; ph < nph; ++ph) {
        const TA* Ap = (ph ? A2 : A1) + b * sAb;
        const TB* Bp = (ph ? B2 : B1) + b * sBb;
        const unsigned int sgn = (ph && neg2) ? 0x80008000u : 0u;
        for (int k0 = 0; k0 < Kp; k0 += 32) {
            uint4 av = load8(Ap + (long long)(bm0 + arow) * sAm + k0 + achk * 8);
            av.x ^= sgn; av.y ^= sgn; av.z ^= sgn; av.w ^= sgn;
            uint4 bv;
            if (BMODE == 0) {
                bv = load8(Bp + (long long)(bn0 + arow) * sBr + k0 + achk * 8);
            } else {
                const int bk = tid >> 3, bnc = tid & 7;
                bv = load8(Bp + (long long)(k0 + bk) * sBr + bn0 + bnc * 8);
            }
            __syncthreads();
            *(uint4*)(&As[arow * 32 + ((achk ^ ((arow >> 1) & 3)) * 8)]) = av;
            if (BMODE == 0) {
                *(uint4*)(&Bs[arow * 32 + ((achk ^ ((arow >> 1) & 3)) * 8)]) = bv;
            } else {
                const int bk = tid >> 3, bnc = tid & 7;
                *(uint2*)(&Bs[bk * 68 + bnc * 8]) = make_uint2(bv.x, bv.y);
                *(uint2*)(&Bs[bk * 68 + bnc * 8 + 4]) = make_uint2(bv.z, bv.w);
            }
            __syncthreads();
            short8v afrag[2], bfrag[2];
#pragma unroll
            for (int i = 0; i < 2; ++i) {
                int r = wr + i * 16 + fr;
                afrag[i] = *(const short8v*)(&As[r * 32 + ((fg ^ ((r >> 1) & 3)) * 8)]);
            }
            if (BMODE == 0) {
#pragma unroll
                for (int j = 0; j < 2; ++j) {
                    int r = wc + j * 16 + fr;
                    bfrag[j] = *(const short8v*)(&Bs[r * 32 + ((fg ^ ((r >> 1) & 3)) * 8)]);
                }
            } else {
#pragma unroll
                for (int j = 0; j < 2; ++j) {
                    int col = wc + j * 16 + fr;
                    short8v v;
#pragma unroll
                    for (int e = 0; e < 8; ++e) v[e] = (short)Bs[(fg * 8 + e) * 68 + col];
                    bfrag[j] = v;
                }
            }
#pragma unroll
            for (int i = 0; i < 2; ++i)
#pragma unroll
                for (int j = 0; j < 2; ++j)
                    acc[i][j] = __builtin_amdgcn_mfma_f32_16x16x32_bf16(afrag[i], bfrag[j], acc[i][j], 0, 0, 0);
        }
    }
#pragma unroll
    for (int i = 0; i < 2; ++i) {
#pragma unroll
        for (int j = 0; j < 2; ++j) {
            int col = bn0 + wc + j * 16 + fr;
            if (col >= N) continue;
#pragma unroll
            for (int r = 0; r < 4; ++r) {
                int row = bm0 + wr + i * 16 + fg * 4 + r;
                if (row >= M) continue;
                float v = acc[i][j][r];
                if (D) v += rdD(D + b * sDb + (long long)row * sDm + col);
                if (act) v = gelu_f(v);
                stO(O + b * sOb + (long long)row * sOm + col, v);
            }
        }
    }
}

// ============ XCD-pair-swizzled gemm_t<0>, batch=1 (R14-proven) ============
template<class TA, class TB, class TD, class TO>
__global__ __launch_bounds__(256) void gemm_ts(
    const TA* __restrict__ A, const TB* __restrict__ B,
    const TD* __restrict__ D, TO* __restrict__ O,
    int M, int N, int Kp, int act,
    long long sAm, long long sBr,
    long long sDm, long long sOm)
{
    __shared__ __align__(16) u16 As[64 * 32];
    __shared__ __align__(16) u16 Bs[64 * 32];
    const int tid = threadIdx.x;
    int lid = blockIdx.x + (int)gridDim.x * blockIdx.y;
    int total = (int)(gridDim.x * gridDim.y);
    int nx, ny;
    if ((lid & ~15) + 16 <= total) {
        nx = (lid >> 3) & 1;
        ny = ((lid >> 4) << 3) + (lid & 7);
    } else {
        nx = lid & 1;
        ny = lid >> 1;
    }
    const int bm0 = ny * 64;
    const int bn0 = nx * 64;
    const int lane = tid & 63;
    const int wave = tid >> 6;
    const int wr = (wave >> 1) * 32;
    const int wc = (wave & 1) * 32;
    const int fr = lane & 15;
    const int fg = lane >> 4;
    const int arow = tid >> 2, achk = tid & 3;
    const int aswz = (achk ^ ((arow >> 1) & 3)) * 8;

    f32x4 acc[2][2];
#pragma unroll
    for (int i = 0; i < 2; ++i)
#pragma unroll
        for (int j = 0; j < 2; ++j) acc[i][j] = (f32x4){0.f, 0.f, 0.f, 0.f};

    for (int k0 = 0; k0 < Kp; k0 += 32) {
        uint4 av = load8(A + (long long)(bm0 + arow) * sAm + k0 + achk * 8);
        uint4 bv = load8(B + (long long)(bn0 + arow) * sBr + k0 + achk * 8);
        __syncthreads();
        *(uint4*)(&As[arow * 32 + aswz]) = av;
        *(uint4*)(&Bs[arow * 32 + aswz]) = bv;
        __syncthreads();
        short8v afrag[2], bfrag[2];
#pragma unroll
        for (int i = 0; i < 2; ++i) {
            int r = wr + i * 16 + fr;
            afrag[i] = *(const short8v*)(&As[r * 32 + ((fg ^ ((r >> 1) & 3)) * 8)]);
        }
#pragma unroll
        for (int j = 0; j < 2; ++j) {
            int r = wc + j * 16 + fr;
            bfrag[j] = *(const short8v*)(&Bs[r * 32 + ((fg ^ ((r >> 1) & 3)) * 8)]);
        }
#pragma unroll
        for (int i = 0; i < 2; ++i)
#pragma unroll
            for (int j = 0; j < 2; ++j)
                acc[i][j] = __builtin_amdgcn_mfma_f32_16x16x32_bf16(afrag[i], bfrag[j], acc[i][j], 0, 0, 0);
    }
#pragma unroll
    for (int i = 0; i < 2; ++i) {
#pragma unroll
        for (int j = 0; j < 2; ++j) {
            int col = bn0 + wc + j * 16 + fr;
            if (col >= N) continue;
#pragma unroll
            for (int r = 0; r < 4; ++r) {
                int row = bm0 + wr + i * 16 + fg * 4 + r;
                if (row >= M) continue;
                float v = acc[i][j][r];
                if (D) v += rdD(D + (long long)row * sDm + col);
                if (act) v = gelu_f(v);
                stO(O + (long long)row * sOm + col, v);
            }
        }
    }
}

// ============ fused MLP: O = m2 . gelu(m1 . A) + D, hidden kept in LDS ============
// Bit-exact vs the split gemm_t pair (same f2bf rounding, same k order).
template<class TA, class TD, class TO>
__global__ __launch_bounds__(256) void gemm_mlp(
    const TA* __restrict__ A, const u16* __restrict__ W1, const u16* __restrict__ W2,
    const TD* __restrict__ D, TO* __restrict__ O,
    int M, long long sAm, long long sDm, long long sOm)
{
    __shared__ __align__(16) u16 As4[4][64 * 32];   // 16 KB: A tile [64][128]
    __shared__ __align__(16) u16 Hs[8][64 * 32];    // 32 KB: hidden [64][256] bf16
    const int tid = threadIdx.x;
    const int bm0 = blockIdx.x * 64;
    const int lane = tid & 63;
    const int wave = tid >> 6;
    const int wr = (wave >> 1) * 32;
    const int wc = (wave & 1) * 32;
    const int fr = lane & 15;
    const int fg = lane >> 4;
    const int arow = tid >> 2, achk = tid & 3;
    const int aswz = (achk ^ ((arow >> 1) & 3)) * 8;

#pragma unroll
    for (int kt = 0; kt < 4; ++kt) {
        uint4 av = load8(A + (long long)(bm0 + arow) * sAm + kt * 32 + achk * 8);
        *(uint4*)(&As4[kt][arow * 32 + aswz]) = av;
    }
    __syncthreads();

#pragma unroll
    for (int nb = 0; nb < 4; ++nb) {
        f32x4 acc[2][2];
#pragma unroll
        for (int i = 0; i < 2; ++i)
#pragma unroll
            for (int j = 0; j < 2; ++j) acc[i][j] = (f32x4){0.f, 0.f, 0.f, 0.f};
#pragma unroll
        for (int kt = 0; kt < 4; ++kt) {
            short8v af[2], bf[2];
#pragma unroll
            for (int i = 0; i < 2; ++i) {
                int r = wr + i * 16 + fr;
                af[i] = *(const short8v*)(&As4[kt][r * 32 + ((fg ^ ((r >> 1) & 3)) * 8)]);
            }
#pragma unroll
            for (int j = 0; j < 2; ++j) {
                int col = wc + nb * 64 + j * 16 + fr;
                bf[j] = *(const short8v*)(W1 + (long long)col * 128 + kt * 32 + fg * 8);
            }
#pragma unroll
            for (int i = 0; i < 2; ++i)
#pragma unroll
                for (int j = 0; j < 2; ++j)
                    acc[i][j] = __builtin_amdgcn_mfma_f32_16x16x32_bf16(af[i], bf[j], acc[i][j], 0, 0, 0);
        }
#pragma unroll
        for (int i = 0; i < 2; ++i)
#pragma unroll
            for (int j = 0; j < 2; ++j) {
                int col = wc + nb * 64 + j * 16 + fr;
                int kt2 = col >> 5, kc = (col >> 3) & 3, ke = col & 7;
#pragma unroll
                for (int r = 0; r < 4; ++r) {
                    int row = wr + i * 16 + fg * 4 + r;
                    Hs[kt2][row * 32 + ((kc ^ ((row >> 1) & 3)) * 8) + ke] = f2bf(gelu_f(acc[i][j][r]));
                }
            }
    }
    __syncthreads();

#pragma unroll
    for (int nb2 = 0; nb2 < 2; ++nb2) {
        f32x4 acc2[2][2];
#pragma unroll
        for (int i = 0; i < 2; ++i)
#pragma unroll
            for (int j = 0; j < 2; ++j) acc2[i][j] = (f32x4){0.f, 0.f, 0.f, 0.f};
#pragma unroll
        for (int kt = 0; kt < 8; ++kt) {
            short8v af[2], bf[2];
#pragma unroll
            for (int i = 0; i < 2; ++i) {
                int r = wr + i * 16 + fr;
                af[i] = *(const short8v*)(&Hs[kt][r * 32 + ((fg ^ ((r >> 1) & 3)) * 8)]);
            }
#pragma unroll
            for (int j = 0; j < 2; ++j) {
                int col = nb2 * 64 + wc + j * 16 + fr;
                bf[j] = *(const short8v*)(W2 + (long long)col * 256 + kt * 32 + fg * 8);
            }
#pragma unroll
            for (int i = 0; i < 2; ++i)
#pragma unroll
                for (int j = 0; j < 2; ++j)
                    acc2[i][j] = __builtin_amdgcn_mfma_f32_16x16x32_bf16(af[i], bf[j], acc2[i][j], 0, 0, 0);
        }
#pragma unroll
        for (int i = 0; i < 2; ++i) {
#pragma unroll
            for (int j = 0; j < 2; ++j) {
                int col = nb2 * 64 + wc + j * 16 + fr;
#pragma unroll
                for (int r = 0; r < 4; ++r) {
                    int row = bm0 + wr + i * 16 + fg * 4 + r;
                    if (row >= M) continue;
                    float v = acc2[i][j][r];
                    if (D) v += rdD(D + (long long)row * sDm + col);
                    stO(O + (long long)row * sOm + col, v);
                }
            }
        }
    }
}

// ============ fused dual-output MFMA GEMM (derived from gemm_t) ============
template<int BMODE, int MODE, class TA, class TB, class TO>
__global__ __launch_bounds__(256) void gemm_t2(
    const TA* __restrict__ A1, const TA* __restrict__ A2,
    const TB* __restrict__ B1, const TB* __restrict__ B2,
    TO* __restrict__ O1, TO* __restrict__ O2,
    int M, int N, int Kp, int s2neg,
    long long sAb, long long sAm,
    long long sBb, long long sBr,
    long long sOb, long long sOm)
{
    __shared__ __align__(16) u16 As1[64 * 32], As2[64 * 32];
    __shared__ __align__(16) u16 Bs1[BMODE ? 32 * 68 : 64 * 32];
    __shared__ __align__(16) u16 Bs2[(MODE == 1) ? 16 : (BMODE ? 32 * 68 : 64 * 32)];
    const int tid = threadIdx.x;
    const long long b = blockIdx.z;
    const int bm0 = blockIdx.y * 64;
    const int bn0 = blockIdx.x * 64;
    const int lane = tid & 63;
    const int wave = tid >> 6;
    const int wr = (wave >> 1) * 32;
    const int wc = (wave & 1) * 32;
    const int fr = lane & 15;
    const int fg = lane >> 4;
    const int arow = tid >> 2, achk = tid & 3;
    const int aswz = (achk ^ ((arow >> 1) & 3)) * 8;

    f32x4 acc1[2][2], acc2[2][2];
#pragma unroll
    for (int i = 0; i < 2; ++i)
#pragma unroll
        for (int j = 0; j < 2; ++j) {
            acc1[i][j] = (f32x4){0.f, 0.f, 0.f, 0.f};
            acc2[i][j] = (f32x4){0.f, 0.f, 0.f, 0.f};
        }

    const TA* A1b = A1 + b * sAb;
    const TA* A2b = A2 + b * sAb;
    const TB* B1b = B1 + b * sBb;
    const TB* B2b = (MODE == 0) ? B2 + b * sBb : B1;

    for (int k0 = 0; k0 < Kp; k0 += 32) {
        long long aoff = (long long)(bm0 + arow) * sAm + k0 + achk * 8;
        uint4 av1 = load8(A1b + aoff);
        uint4 av2 = load8(A2b + aoff);
        uint4 bv1, bv2;
        if (BMODE == 0) {
            long long boff = (long long)(bn0 + arow) * sBr + k0 + achk * 8;
            bv1 = load8(B1b + boff);
            if (MODE == 0) bv2 = load8(B2b + boff);
        } else {
            const int bk = tid >> 3, bnc = tid & 7;
            long long boff = (long long)(k0 + bk) * sBr + bn0 + bnc * 8;
            bv1 = load8(B1b + boff);
            if (MODE == 0) bv2 = load8(B2b + boff);
        }
        __syncthreads();
        *(uint4*)(&As1[arow * 32 + aswz]) = av1;
        *(uint4*)(&As2[arow * 32 + aswz]) = av2;
        if (BMODE == 0) {
            *(uint4*)(&Bs1[arow * 32 + aswz]) = bv1;
            if (MODE == 0) *(uint4*)(&Bs2[arow * 32 + aswz]) = bv2;
        } else {
            const int bk = tid >> 3, bnc = tid & 7;
            *(uint2*)(&Bs1[bk * 68 + bnc * 8]) = make_uint2(bv1.x, bv1.y);
            *(uint2*)(&Bs1[bk * 68 + bnc * 8 + 4]) = make_uint2(bv1.z, bv1.w);
            if (MODE == 0) {
                *(uint2*)(&Bs2[bk * 68 + bnc * 8]) = make_uint2(bv2.x, bv2.y);
                *(uint2*)(&Bs2[bk * 68 + bnc * 8 + 4]) = make_uint2(bv2.z, bv2.w);
            }
        }
        __syncthreads();
        short8v a1f[2], a2f[2], b1f[2], b2f[2];
#pragma unroll
        for (int i = 0; i < 2; ++i) {
            int r = wr + i * 16 + fr;
            int o = r * 32 + ((fg ^ ((r >> 1) & 3)) * 8);
            a1f[i] = *(const short8v*)(&As1[o]);
            a2f[i] = *(const short8v*)(&As2[o]);
        }
        if (BMODE == 0) {
#pragma unroll
            for (int j = 0; j < 2; ++j) {
                int r = wc + j * 16 + fr;
                int o = r * 32 + ((fg ^ ((r >> 1) & 3)) * 8);
                b1f[j] = *(const short8v*)(&Bs1[o]);
                if (MODE == 0) b2f[j] = *(const short8v*)(&Bs2[o]);
            }
        } else {
#pragma unroll
            for (int j = 0; j < 2; ++j) {
                int col = wc + j * 16 + fr;
                short8v v1, v2;
#pragma unroll
                for (int e = 0; e < 8; ++e) {
                    v1[e] = (short)Bs1[(fg * 8 + e) * 68 + col];
                    if (MODE == 0) v2[e] = (short)Bs2[(fg * 8 + e) * 68 + col];
                }
                b1f[j] = v1;
                if (MODE == 0) b2f[j] = v2;
            }
        }
        if (MODE == 1) {
#pragma unroll
            for (int i = 0; i < 2; ++i)
#pragma unroll
                for (int j = 0; j < 2; ++j) {
                    acc1[i][j] = __builtin_amdgcn_mfma_f32_16x16x32_bf16(a1f[i], b1f[j], acc1[i][j], 0, 0, 0);
                    acc2[i][j] = __builtin_amdgcn_mfma_f32_16x16x32_bf16(a2f[i], b1f[j], acc2[i][j], 0, 0, 0);
                }
        } else {
            short8v a2p[2], a2m[2];
#pragma unroll
            for (int i = 0; i < 2; ++i) {
                a2p[i] = s2neg ? negbf(a2f[i]) : a2f[i];
                a2m[i] = s2neg ? a2f[i] : negbf(a2f[i]);
            }
#pragma unroll
            for (int i = 0; i < 2; ++i)
#pragma unroll
                for (int j = 0; j < 2; ++j) {
                    acc1[i][j] = __builtin_amdgcn_mfma_f32_16x16x32_bf16(a1f[i], b1f[j], acc1[i][j], 0, 0, 0);
                    acc1[i][j] = __builtin_amdgcn_mfma_f32_16x16x32_bf16(a2p[i], b2f[j], acc1[i][j], 0, 0, 0);
                    acc2[i][j] = __builtin_amdgcn_mfma_f32_16x16x32_bf16(a1f[i], b2f[j], acc2[i][j], 0, 0, 0);
                    acc2[i][j] = __builtin_amdgcn_mfma_f32_16x16x32_bf16(a2m[i], b1f[j], acc2[i][j], 0, 0, 0);
                }
        }
    }
#pragma unroll
    for (int i = 0; i < 2; ++i) {
#pragma unroll
        for (int j = 0; j < 2; ++j) {
            int col = bn0 + wc + j * 16 + fr;
            if (col >= N) continue;
#pragma unroll
            for (int r = 0; r < 4; ++r) {
                int row = bm0 + wr + i * 16 + fg * 4 + r;
                if (row >= M) continue;
                long long oi = b * sOb + (long long)row * sOm + col;
                stO(O1 + oi, acc1[i][j][r]);
                stO(O2 + oi, acc2[i][j][r]);
            }
        }
    }
}

// ============ DFT matrix generators (bf16, zero-padded) ============
__global__ void gen_fwdW_T(u16* Cm, u16* Sm, int RP, int KP, int W, int MM) {
    int idx = blockIdx.x * blockDim.x + threadIdx.x;
    if (idx >= RP * KP) return;
    int m = idx / KP, w = idx % KP;
    float cv = 0.f, sv = 0.f;
    if (m < MM && w < W) {
        int t = (m * w) % W;
        float arg = 2.0f * (float)t / (float)W;
        float s = 1.0f / sqrtf((float)W);
        cv = cospif(arg) * s; sv = -sinpif(arg) * s;
    }
    Cm[idx] = f2bf(cv); Sm[idx] = f2bf(sv);
}
__global__ void gen_fwdH(u16* Cm, u16* Sm, int RP, int KP, int H) {
    int idx = blockIdx.x * blockDim.x + threadIdx.x;
    if (idx >= RP * KP) return;
    int l = idx / KP, h = idx % KP;
    float cv = 0.f, sv = 0.f;
    if (l < 90 && h < H) {
        int ll = (l < 45) ? l : l + H - 90;
        int t = (ll * h) % H;
        float arg = 2.0f * (float)t / (float)H;
        float s = 1.0f / sqrtf((float)H);
        cv = cospif(arg) * s; sv = sinpif(arg) * s;
    }
    Cm[idx] = f2bf(cv); Sm[idx] = f2bf(sv);
}
__global__ void gen_invH(u16* Cm, u16* Sm, int RP, int KP, int H) {
    int idx = blockIdx.x * blockDim.x + threadIdx.x;
    if (idx >= RP * KP) return;
    int y = idx / KP, l = idx % KP;
    float cv = 0.f, sv = 0.f;
    if (y < H && l < 90) {
        int ll = (l < 45) ? l : l + H - 90;
        int t = (ll * y) % H;
        float arg = 2.0f * (float)t / (float)H;
        float s = 1.0f / sqrtf((float)H);
        cv = cospif(arg) * s; sv = sinpif(arg) * s;
    }
    Cm[idx] = f2bf(cv); Sm[idx] = f2bf(sv);
}
__global__ void gen_invW_T(u16* Cm, u16* Sm, int RP, int KP, int W, int MM) {
    int idx = blockIdx.x * blockDim.x + threadIdx.x;
    if (idx >= RP * KP) return;
    int w = idx / KP, m = idx % KP;
    float cv = 0.f, sv = 0.f;
    if (w < W && m < MM) {
        int t = (m * w) % W;
        float arg = 2.0f * (float)t / (float)W;
        bool nyq = (2 * m == W);
        float wt = (m == 0 || nyq) ? 1.0f : 2.0f;
        float s = wt / sqrtf((float)W);
        cv = cospif(arg) * s;
        sv = nyq ? 0.f : sinpif(arg) * s;
    }
    Cm[idx] = f2bf(cv); Sm[idx] = f2bf(sv);
}

// ============ weight prep ============
__global__ void w2bf(const float* __restrict__ in, u16* __restrict__ out, int R, int K, int rs) {
    int idx = blockIdx.x * blockDim.x + threadIdx.x;
    if (idx >= R * K) return;
    int r = idx / K, c = idx % K;
    out[idx] = f2bf(in[(long long)r * rs + c]);
}
__global__ void transp_sw(const float* __restrict__ in, u16* __restrict__ out) {
    __shared__ float t[32][33];
    int l0 = blockIdx.x * 32, ci0 = blockIdx.y * 32, co = blockIdx.z;
    int tx = threadIdx.x, ty = threadIdx.y;
#pragma unroll
    for (int rr = 0; rr < 4; ++rr) {
        int ci = ci0 + ty + rr * 8;
        int l = l0 + tx;
        t[ty + rr * 8][tx] = (l < 90) ? in[((long long)ci * 128 + co) * 90 + l] : 0.f;
    }
    __syncthreads();
#pragma unroll
    for (int rr = 0; rr < 4; ++rr) {
        int l = l0 + ty + rr * 8;
        int ci = ci0 + tx;
        if (l < 90) out[((long long)l * 128 + co) * 128 + ci] = f2bf(t[tx][ty + rr * 8]);
    }
}

// ============ instance norm ============
__global__ __launch_bounds__(256) void stats_cl_bf(const u16* __restrict__ x, long long P,
                                                   float2* __restrict__ part, int nch) {
    int chunk = blockIdx.x;
    int c = threadIdx.x & 127;
    int h = threadIdx.x >> 7;
    long long beg = P * chunk / nch, end = P * (chunk + 1) / nch;
    float s = 0.f, q = 0.f;
    long long p = beg + h;
    for (; p + 14 < end; p += 16) {
        float v[8];
#pragma unroll
        for (int u = 0; u < 8; ++u) v[u] = bf2f(x[(p + 2 * u) * 128 + c]);
#pragma unroll
        for (int u = 0; u < 8; ++u) { s += v[u]; q += v[u] * v[u]; }
    }
    for (; p < end; p += 2) {
        float v = bf2f(x[p * 128 + c]);
        s += v; q += v * v;
    }
    __shared__ float rs[256], rq[256];
    rs[threadIdx.x] = s; rq[threadIdx.x] = q;
    __syncthreads();
    if (threadIdx.x < 128)
        part[(long long)c * nch + chunk] = make_float2(rs[c] + rs[c + 128], rq[c] + rq[c + 128]);
}
__global__ __launch_bounds__(256) void stats_cl_f32(const float* __restrict__ x, long long P,
                                                    float2* __restrict__ part, int nch) {
    int chunk = blockIdx.x;
    long long beg = P * chunk / nch, end = P * (chunk + 1) / nch;
    int c32 = threadIdx.x & 31;
    int pr  = threadIdx.x >> 5;
    float s[4], q[4];
#pragma unroll
    for (int k = 0; k < 4; ++k) { s[k] = 0.f; q[k] = 0.f; }
    for (long long p = beg + pr; p < end; p += 8) {
        float4 v = *(const float4*)(x + p * 128 + c32 * 4);
        float e[4] = {v.x, v.y, v.z, v.w};
#pragma unroll
        for (int k = 0; k < 4; ++k) { s[k] += e[k]; q[k] += e[k] * e[k]; }
    }
#pragma unroll
    for (int k = 0; k < 4; ++k) {
        s[k] += __shfl_xor(s[k], 32); q[k] += __shfl_xor(q[k], 32);
    }
    __shared__ float2 lds[4][128];
    int wv = threadIdx.x >> 6, lane = threadIdx.x & 63;
    if (lane < 32) {
#pragma unroll
        for (int k = 0; k < 4; ++k) lds[wv][lane * 4 + k] = make_float2(s[k], q[k]);
    }
    __syncthreads();
    if (threadIdx.x < 128) {
        float2 a = lds[0][threadIdx.x], b2 = lds[1][threadIdx.x];
        float2 c2 = lds[2][threadIdx.x], d2 = lds[3][threadIdx.x];
        part[(long long)threadIdx.x * nch + chunk] =
            make_float2(a.x + b2.x + c2.x + d2.x, a.y + b2.y + c2.y + d2.y);
    }
}
__global__ void stats_fin(const float2* __restrict__ part, int nch, float Pf,
                          const float* __restrict__ w, const float* __restrict__ b,
                          float2* __restrict__ st) {
    int c = threadIdx.x;
    float s = 0.f, q = 0.f;
    for (int i = 0; i < nch; ++i) { float2 p = part[(long long)c * nch + i]; s += p.x; q += p.y; }
    float mu = s / Pf;
    float var = q / Pf - mu * mu;
    float inv = rsqrtf(var + 1e-5f);
    float sc = w[c] * inv;
    st[c] = make_float2(sc, b[c] - mu * sc);
}
__global__ __launch_bounds__(256) void norm_apply_bf(const u16* __restrict__ src, u16* __restrict__ dst,
                                                     long long n8, const float2* __restrict__ st) {
    long long i = (long long)blockIdx.x * 256 + threadIdx.x;
    if (i >= n8) return;
    int c0 = (int)((i * 8) & 127);
    uint4 v = *(const uint4*)(src + i * 8);
    union { uint4 u; u16 e[8]; } in, out;
    in.u = v;
#pragma unroll
    for (int k = 0; k < 8; ++k) {
        float2 s = st[c0 + k];
        out.e[k] = f2bf(bf2f(in.e[k]) * s.x + s.y);
    }
    *(uint4*)(dst + i * 8) = out.u;
}
__global__ __launch_bounds__(256) void norm_apply_f32(const float4* __restrict__ src, float4* __restrict__ dst,
                                                      long long n4, const float2* __restrict__ st) {
    long long i = (long long)blockIdx.x * 256 + threadIdx.x;
    if (i >= n4) return;
    int c0 = (int)((i * 4) & 127);
    float4 v = src[i];
    float2 s0 = st[c0], s1 = st[c0 + 1], s2 = st[c0 + 2], s3 = st[c0 + 3];
    v.x = v.x * s0.x + s0.y;
    v.y = v.y * s1.x + s1.y;
    v.z = v.z * s2.x + s2.y;
    v.w = v.w * s3.x + s3.y;
    dst[i] = v;
}

// ============ encoder front / fused decoder ============
__global__ __launch_bounds__(256) void enc_front(const float* __restrict__ x, const float* __restrict__ w1,
                                                 u16* __restrict__ out, long long P) {
    long long idx = (long long)blockIdx.x * 256 + threadIdx.x;
    if (idx >= P * 16) return;
    long long p = idx >> 4;
    int c0 = (int)(idx & 15) * 8;
    float x0 = x[p], x1 = x[P + p];
    union { uint4 u; u16 e[8]; } o;
#pragma unroll
    for (int k = 0; k < 8; ++k) {
        int c = c0 + k;
        o.e[k] = f2bf(gelu_f(w1[c * 2] * x0 + w1[c * 2 + 1] * x1));
    }
    *(uint4*)(out + p * 128 + c0) = o.u;
}
__global__ __launch_bounds__(256) void dec_fuse(const u16* __restrict__ d1, const float* __restrict__ dw1,
                                                const float* __restrict__ x, const float* __restrict__ w2,
                                                float* __restrict__ out, long long P) {
    __shared__ float w2s[256];
    __shared__ float dxs[256];
    w2s[threadIdx.x] = w2[threadIdx.x];
    {
        int c = threadIdx.x >> 1, h = threadIdx.x & 1;
        dxs[threadIdx.x] = dw1[c * 130 + 128 + h];
    }
    __syncthreads();
    int lane = threadIdx.x & 63;
    long long pix = (long long)blockIdx.x * 4 + (threadIdx.x >> 6);
    float x0 = x[pix], x1 = x[P + pix];
    unsigned int pr = *(const unsigned int*)(d1 + pix * 128 + lane * 2);
    float b0 = bf2f(f2bf(gelu_f(bf2f((u16)(pr & 0xFFFF)) + dxs[4 * lane]     * x0 + dxs[4 * lane + 1] * x1)));
    float b1 = bf2f(f2bf(gelu_f(bf2f((u16)(pr >> 16))    + dxs[4 * lane + 2] * x0 + dxs[4 * lane + 3] * x1)));
    float s0 = b0 * w2s[lane * 2] + b1 * w2s[lane * 2 + 1];
    float s1 = b0 * w2s[128 + lane * 2] + b1 * w2s[128 + lane * 2 + 1];
#pragma unroll
    for (int off = 1; off < 64; off <<= 1) {
        s0 += __shfl_xor(s0, off);
        s1 += __shfl_xor(s1, off);
    }
    if (lane == 0) { out[pix] = s0; out[P + pix] = s1; }
}

__global__ void zero_out(float* p, long long n) {
    long long i = (long long)blockIdx.x * 256 + threadIdx.x;
    if (i < n) p[i] = 0.f;
}

// ============ host ============
extern "C" void kernel_launch(void* const* d_in, const int* in_sizes, int n_in,
                              void* d_out, int out_size, void* d_ws, size_t ws_size,
                              hipStream_t stream)
{
    const int HF = 360, WF = 720, HL = 90, WL = 180, C = 128, MM = 91;
    const long long PF = (long long)HF * WF;
    const long long PL = (long long)HL * WL;
    (void)in_sizes; (void)n_in;

    const float* x      = (const float*)d_in[0];
    const float* enc_w1 = (const float*)d_in[1];
    const float* enc_w2 = (const float*)d_in[2];
    const float* n0w    = (const float*)d_in[3];
    const float* n0b    = (const float*)d_in[4];
    const float* swr    = (const float*)d_in[5];
    const float* swi    = (const float*)d_in[6];
    const float* iw     = (const float*)d_in[7];
    const float* n1w    = (const float*)d_in[8];
    const float* n1b    = (const float*)d_in[9];
    const float* mw1    = (const float*)d_in[10];
    const float* mw2    = (const float*)d_in[11];
    const float* dec_w1 = (const float*)d_in[12];
    const float* dec_w2 = (const float*)d_in[13];
    float* outp = (float*)d_out;

    u16* ws = (u16*)d_ws;
    long long off = 0;
    auto alloc = [&](long long n) { u16* p = ws + off; off += (n + 31) & ~31LL; return p; };
    auto allocF = [&](long long n) { return (float*)alloc(2 * n); };

    u16*   FULL = alloc(PF * C);
    u16*   RES  = alloc(PF * C);
    u16*   S1r  = alloc(96LL * 384 * 128);
    u16*   S1i  = alloc(96LL * 384 * 128);
    float* Xr   = allocF(96LL * 96 * 128);
    float* Xi   = allocF(96LL * 96 * 128);
    float* Yr   = allocF(96LL * 96 * 128);
    float* Yi   = allocF(96LL * 96 * 128);
    u16*   G1r  = alloc(360LL * 96 * 128);
    u16*   G1i  = alloc(360LL * 96 * 128);
    u16*   G3r  = alloc(360LL * 96 * 128);
    u16*   G3i  = alloc(360LL * 96 * 128);
    float* Rlo  = allocF(PL * C);
    float* L0   = allocF(PL * C);
    u16*   WtR  = alloc(90LL * 128 * 128);
    u16*   WtI  = alloc(90LL * 128 * 128);
    u16* encw2b = alloc(128 * 128);
    u16* iwb    = alloc(128 * 128);
    u16* m1b    = alloc(256 * 128);
    u16* m2b    = alloc(128 * 256);
    u16* dw1b   = alloc(128 * 128);
    u16* CwTc_h = alloc(128 * 736); u16* CwTs_h = alloc(128 * 736);
    u16* CwTc_l = alloc(128 * 192); u16* CwTs_l = alloc(128 * 192);
    u16* Chc_h  = alloc(128 * 384); u16* Chs_h  = alloc(128 * 384);
    u16* Chc_l  = alloc(128 * 96);  u16* Chs_l  = alloc(128 * 96);
    u16* C2c_h  = alloc(384 * 96);  u16* C2s_h  = alloc(384 * 96);
    u16* C2c_l  = alloc(128 * 96);  u16* C2s_l  = alloc(128 * 96);
    u16* CwIc_h = alloc(768 * 96);  u16* CwIs_h = alloc(768 * 96);
    u16* CwIc_l = alloc(192 * 96);  u16* CwIs_l = alloc(192 * 96);
    float2* PART = (float2*)alloc(128 * 256 * 4);
    float2* STb  = (float2*)alloc(128 * 4);
    alloc(64 * 1024);   // slack for staged over-reads

    if ((size_t)(off * 2) > ws_size) {
        zero_out<<<(int)((out_size + 255) / 256), 256, 0, stream>>>(outp, out_size);
        return;
    }

    auto grid3 = [](int M, int N, int batch) {
        return dim3((unsigned)((N + 63) / 64), (unsigned)((M + 63) / 64), (unsigned)batch);
    };
    auto inormB = [&](const u16* src, u16* dst, long long P, int nch,
                      const float* w, const float* b) {
        stats_cl_bf<<<nch, 256, 0, stream>>>(src, P, PART, nch);
        stats_fin<<<1, 128, 0, stream>>>(PART, nch, (float)P, w, b, STb);
        long long n8 = P * 128 / 8;
        norm_apply_bf<<<(int)((n8 + 255) / 256), 256, 0, stream>>>(src, dst, n8, STb);
    };
    auto inormF = [&](const float* src, float* dst, long long P, int nch,
                      const float* w, const float* b) {
        stats_cl_f32<<<nch, 256, 0, stream>>>(src, P, PART, nch);
        stats_fin<<<1, 128, 0, stream>>>(PART, nch, (float)P, w, b, STb);
        long long n4 = P * 128 / 4;
        norm_apply_f32<<<(int)((n4 + 255) / 256), 256, 0, stream>>>(
            (const float4*)src, (float4*)dst, n4, STb);
    };

    const u16* nullU = nullptr;
    const float* nullF = nullptr;

    // ---- DFT matrices ----
    {
        int n;
        n = 128 * 736; gen_fwdW_T<<<(n + 255) / 256, 256, 0, stream>>>(CwTc_h, CwTs_h, 128, 736, 720, MM);
        n = 128 * 192; gen_fwdW_T<<<(n + 255) / 256, 256, 0, stream>>>(CwTc_l, CwTs_l, 128, 192, 180, MM);
        n = 128 * 384; gen_fwdH<<<(n + 255) / 256, 256, 0, stream>>>(Chc_h, Chs_h, 128, 384, 360);
        n = 128 * 96;  gen_fwdH<<<(n + 255) / 256, 256, 0, stream>>>(Chc_l, Chs_l, 128, 96, 90);
        n = 384 * 96;  gen_invH<<<(n + 255) / 256, 256, 0, stream>>>(C2c_h, C2s_h, 384, 96, 360);
        n = 128 * 96;  gen_invH<<<(n + 255) / 256, 256, 0, stream>>>(C2c_l, C2s_l, 128, 96, 90);
        n = 768 * 96;  gen_invW_T<<<(n + 255) / 256, 256, 0, stream>>>(CwIc_h, CwIs_h, 768, 96, 720, MM);
        n = 192 * 96;  gen_invW_T<<<(n + 255) / 256, 256, 0, stream>>>(CwIc_l, CwIs_l, 192, 96, 180, MM);
        n = 128 * 128; w2bf<<<(n + 255) / 256, 256, 0, stream>>>(enc_w2, encw2b, 128, 128, 128);
        n = 128 * 128; w2bf<<<(n + 255) / 256, 256, 0, stream>>>(dec_w1, dw1b, 128, 128, 130);
    }

    // ---- encoder ----
    enc_front<<<(int)((PF * 16 + 255) / 256), 256, 0, stream>>>(x, enc_w1, RES, PF);
    gemm_ts<u16, u16, u16, u16><<<grid3((int)PF, 128, 1), 256, 0, stream>>>(
        RES, encw2b, nullU, FULL, (int)PF, 128, 128, 0, 128, 128, 0, 128);

    const long long s96 = 96LL * 128;

    for (int l = 0; l < 4; ++l) {
        const bool inHi = (l == 0), outHi = (l == 3);
        const int Hin = inHi ? HF : HL, Win = inHi ? WF : WL;
        const int Hout = outHi ? HF : HL, Wout = outHi ? WF : WL;
        const long long Pout = (long long)Hout * Wout;
        const int hdim = inHi ? 384 : 96;
        const int Wp = inHi ? 736 : 192;
        const int hp = inHi ? 384 : 96;
        const u16* CwTc = inHi ? CwTc_h : CwTc_l;  const u16* CwTs = inHi ? CwTs_h : CwTs_l;
        const u16* Chc  = inHi ? Chc_h  : Chc_l;   const u16* Chs  = inHi ? Chs_h  : Chs_l;
        const u16* C2c  = outHi ? C2c_h : C2c_l;   const u16* C2s  = outHi ? C2s_h : C2s_l;
        const u16* CwIc = outHi ? CwIc_h : CwIc_l; const u16* CwIs = outHi ? CwIs_h : CwIs_l;

        {
            dim3 gt(3, 4, 128); dim3 bt(32, 8);
            transp_sw<<<gt, bt, 0, stream>>>(swr + (long long)l * C * C * 90, WtR);
            transp_sw<<<gt, bt, 0, stream>>>(swi + (long long)l * C * C * 90, WtI);
            int n = 128 * 128; w2bf<<<(n + 255) / 256, 256, 0, stream>>>(iw + (long long)l * C * C, iwb, 128, 128, 128);
            n = 256 * 128; w2bf<<<(n + 255) / 256, 256, 0, stream>>>(mw1 + (long long)l * 256 * C, m1b, 256, 128, 128);
            n = 128 * 256; w2bf<<<(n + 255) / 256, 256, 0, stream>>>(mw2 + (long long)l * C * 256, m2b, 128, 256, 256);
        }

        if (inHi) {
            inormB(FULL, RES, PF, 256, n0w + l * C, n0b + l * C);
            gemm_t2<1, 1, u16, u16, u16><<<grid3(96, 128, Hin), 256, 0, stream>>>(
                CwTc, CwTs, RES, nullU, S1r, S1i, 96, 128, Wp, 0,
                0, Wp, (long long)Win * 128, 128, 128, (long long)hdim * 128);
        } else {
            inormF(Rlo, L0, PL, 128, n0w + l * C, n0b + l * C);
            gemm_t2<1, 1, u16, float, u16><<<grid3(96, 128, Hin), 256, 0, stream>>>(
                CwTc, CwTs, L0, nullF, S1r, S1i, 96, 128, Wp, 0,
                0, Wp, (long long)Win * 128, 128, 128, (long long)hdim * 128);
        }

        gemm_t2<1, 0, u16, u16, float><<<grid3(96, 128, 96), 256, 0, stream>>>(
            Chc, Chs, S1r, S1i, Xr, Xi, 96, 128, hp, 0,
            0, hp, (long long)hdim * 128, 128, 128, s96);

        if (inHi || outHi) {
            gemm_t2<1, 0, u16, float, u16><<<grid3(Hout, 128, 96), 256, 0, stream>>>(
                C2c, C2s, Xr, Xi, G3r, G3i, Hout, 128, 96, 1,
                0, 96, 128, s96, 128, s96);
        }

        gemm_t2<0, 0, float, u16, float><<<grid3(96, 128, 90), 256, 0, stream>>>(
            Xr, Xi, WtR, WtI, Yr, Yi, 96, 128, 128, 1,
            s96, 128, 128LL * 128, 128, 128, s96);

        gemm_t2<1, 0, u16, float, u16><<<grid3(Hout, 128, 96), 256, 0, stream>>>(
            C2c, C2s, Yr, Yi, G1r, G1i, Hout, 128, 96, 1,
            0, 96, s96, 128, 128, s96);

        if (!outHi) {
            gemm_t<1, u16, u16, u16, float><<<grid3(Wout, 128, Hout), 256, 0, stream>>>(
                CwIc, G1r, CwIs, G1i, nullU, Rlo, Wout, 128, 96, 1, 0,
                0, 96, s96, 128, 0, 0, (long long)Wout * 128, 128);
            if (inHi)
                gemm_t<1, u16, u16, u16, float><<<grid3(Wout, 128, Hout), 256, 0, stream>>>(
                    CwIc, G3r, CwIs, G3i, nullU, L0, Wout, 128, 96, 1, 0,
                    0, 96, s96, 128, 0, 0, (long long)Wout * 128, 128);
            gemm_t<0, float, u16, float, float><<<grid3((int)Pout, 128, 1), 256, 0, stream>>>(
                L0, iwb, nullF, nullU, Rlo, Rlo, (int)Pout, 128, 128, 0, 1,
                0, 128, 0, 128, 0, 128, 0, 128);
            inormF(Rlo, Rlo, Pout, 128, n1w + l * C, n1b + l * C);
            gemm_mlp<float, float, float><<<dim3((unsigned)((Pout + 63) / 64)), 256, 0, stream>>>(
                Rlo, m1b, m2b, L0, Rlo, (int)Pout, 128, 128, 128);
        } else {
            gemm_t<1, u16, u16, u16, u16><<<grid3(Wout, 128, Hout), 256, 0, stream>>>(
                CwIc, G1r, CwIs, G1i, nullU, FULL, Wout, 128, 96, 1, 0,
                0, 96, s96, 128, 0, 0, (long long)Wout * 128, 128);
            gemm_t<1, u16, u16, u16, u16><<<grid3(Wout, 128, Hout), 256, 0, stream>>>(
                CwIc, G3r, CwIs, G3i, nullU, RES, Wout, 128, 96, 1, 0,
                0, 96, s96, 128, 0, 0, (long long)Wout * 128, 128);
            gemm_ts<u16, u16, u16, u16><<<grid3((int)Pout, 128, 1), 256, 0, stream>>>(
                RES, iwb, FULL, FULL, (int)Pout, 128, 128, 1, 128, 128, 128, 128);
            inormB(FULL, FULL, Pout, 256, n1w + l * C, n1b + l * C);
            gemm_mlp<u16, u16, u16><<<dim3((unsigned)((Pout + 63) / 64)), 256, 0, stream>>>(
                FULL, m1b, m2b, RES, FULL, (int)Pout, 128, 128, 128);
        }
    }

    // ---- decoder (fused dec_mid + dec_back) ----
    gemm_ts<u16, u16, u16, u16><<<grid3((int)PF, 128, 1), 256, 0, stream>>>(
        FULL, dw1b, nullU, RES, (int)PF, 128, 128, 0, 128, 128, 0, 128);
    dec_fuse<<<(int)(PF / 4), 256, 0, stream>>>(RES, dec_w1, x, dec_w2, outp, PF);
}